// Round 8
// baseline (238.471 us; speedup 1.0000x reference)
//
#include <hip/hip_runtime.h>
#include <stdint.h>

// GCN: out = relu(adj @ (x @ W) + b)
// x:[32,1024,128] f32, adj:[32,1024,1024] f32, W:[128,128] f32, b:[128] f32
// v8b: identical to v8 (round-7 bench was an infra failure, not a kernel
//   verdict; OOB/deadlock audit clean). k2 = quad-buffered global_load_lds
//   pipeline, depth-3 prefetch, counted s_waitcnt vmcnt(8) + raw s_barrier
//   (NEVER vmcnt(0) in main loop) — the m201/T4 pattern. Model: k2 is
//   BW-delay-product bound (~10-25 KB/CU must stay in flight); prior variants
//   drained in-flight to 0 each K-step (syncthreads) or let the compiler sink
//   reg-dest loads (VGPR=48/56). Steady state here: 3 tiles x 4 DMAs/thread
//   in flight = 96 KB/CU. LDS content is chunk-column-major (slot =
//   chunk*rows + row) via per-lane DMA SOURCE permutation, linear dest
//   (rule 21) -> lane-contiguous b128 reads. Buf reuse safe: STAGE(kb+3)
//   hits buf((kb-1)&3), last read before barrier(kb). K-chunk order ascending
//   (BK=32 = old BK=64 s-substeps) -> bit-identical output.
// k1 stays LDS-free streaming (~3.5us, ~HBM peak).

typedef short bf16x8 __attribute__((ext_vector_type(8)));       // 8 bf16 (4 VGPRs)
typedef float f32x4 __attribute__((ext_vector_type(4)));
typedef unsigned short u16x8 __attribute__((ext_vector_type(8)));

__device__ __forceinline__ unsigned short f2bf(float f) {
    uint32_t u = __builtin_bit_cast(uint32_t, f);
    u += 0x7FFFu + ((u >> 16) & 1u);   // RTNE
    return (unsigned short)(u >> 16);
}

__device__ __forceinline__ bf16x8 cvt8(f32x4 v0, f32x4 v1) {
    u16x8 p;
    p[0] = f2bf(v0.x); p[1] = f2bf(v0.y); p[2] = f2bf(v0.z); p[3] = f2bf(v0.w);
    p[4] = f2bf(v1.x); p[5] = f2bf(v1.y); p[6] = f2bf(v1.z); p[7] = f2bf(v1.w);
    return __builtin_bit_cast(bf16x8, p);
}

// async 16B global -> LDS DMA (no VGPR round trip; size must be literal 16)
#define GLD16(g, l)                                                         \
    __builtin_amdgcn_global_load_lds(                                       \
        (const __attribute__((address_space(1))) unsigned int*)(g),         \
        (__attribute__((address_space(3))) unsigned int*)(l), 16, 0, 0)

// ---------------- k0: WT[h][f] = bf16(W[f][h]) ----------------
__global__ __launch_bounds__(256) void k0_wt(const float* __restrict__ W,
                                             unsigned short* __restrict__ WT) {
    int o = blockIdx.x * 256 + threadIdx.x;  // flat over [h][f]
    int h = o >> 7, f = o & 127;
    WT[o] = f2bf(W[f * 128 + h]);
}

// ---------------- k1: ST[b][h][m] = sum_f WT[h][f] * x[b][m][f] ----------------
__global__ __launch_bounds__(256) void k1_support(const float* __restrict__ x,
                                                  const unsigned short* __restrict__ WT,
                                                  unsigned short* __restrict__ ST) {
    int t = threadIdx.x;
    int wv = t >> 6, lane = t & 63, l16 = lane & 15, quad = lane >> 4;
    int wave_h = (wv & 1) * 64, wave_m = (wv >> 1) * 32;
    int node_base = blockIdx.x * 64;
    const float* xb = x + (size_t)node_base * 128;

    f32x4 acc[4][2];
#pragma unroll
    for (int ht = 0; ht < 4; ++ht)
#pragma unroll
        for (int mt = 0; mt < 2; ++mt) acc[ht][mt] = 0.f;

#pragma unroll
    for (int s = 0; s < 4; ++s) {
        int ko = s * 32 + quad * 8;
        bf16x8 a[4], bb[2];
#pragma unroll
        for (int ht = 0; ht < 4; ++ht)
            a[ht] = *(const bf16x8*)&WT[(wave_h + ht * 16 + l16) * 128 + ko];
#pragma unroll
        for (int mt = 0; mt < 2; ++mt) {
            const float* xr = xb + (size_t)(wave_m + mt * 16 + l16) * 128 + ko;
            bb[mt] = cvt8(*(const f32x4*)xr, *(const f32x4*)(xr + 4));
        }
#pragma unroll
        for (int ht = 0; ht < 4; ++ht)
#pragma unroll
            for (int mt = 0; mt < 2; ++mt)
                acc[ht][mt] = __builtin_amdgcn_mfma_f32_16x16x32_bf16(
                    a[ht], bb[mt], acc[ht][mt], 0, 0, 0);
    }

    int batch = blockIdx.x >> 4;
    int m_in_b = (blockIdx.x & 15) * 64;
#pragma unroll
    for (int ht = 0; ht < 4; ++ht)
#pragma unroll
        for (int mt = 0; mt < 2; ++mt) {
            int mcol = wave_m + mt * 16 + l16;
#pragma unroll
            for (int r = 0; r < 4; ++r) {
                int h = wave_h + ht * 16 + quad * 4 + r;
                ST[(((size_t)batch * 128 + h) << 10) + m_in_b + mcol] =
                    f2bf(acc[ht][mt][r]);
            }
        }
}

// ---------------- k2: out[b][m][n] = relu(sum_k adj[b][m][k]*S[b][k][n] + bias[n]) ----
// 64m x 128n per block, grid 512 (XCD-swizzled), 4 waves (32m x 64n), BK=32.
// LDS: As[4][8KB] f32 tiles, Bs[4][8KB] bf16 tiles (64 KB total).
// Chunk-column-major content: As slot o holds (row=o&63, f32chunk=o>>6);
//                             Bs slot o holds (row=o&127, bf16chunk=o>>7).
__global__ __launch_bounds__(256, 2) void k2_gcn(const float* __restrict__ adj,
                                                 const unsigned short* __restrict__ ST,
                                                 const float* __restrict__ bias,
                                                 float* __restrict__ out) {
    __shared__ __align__(16) char As[4][8192];
    __shared__ __align__(16) char Bs[4][8192];
    int t = threadIdx.x;
    int bid = (int)blockIdx.x;
    int orig = (bid & 7) * 64 + (bid >> 3);   // T1: 4 batches per XCD, bijective
    int batch = orig >> 4;
    int mbase = (orig & 15) * 64;
    int wv = t >> 6, lane = t & 63, l16 = lane & 15, quad = lane >> 4;
    int wave_m = (wv & 1) * 32, wave_n = (wv >> 1) * 64;

    const char* adjB = (const char*)(adj + ((size_t)batch * 1024 + mbase) * 1024);
    const char* stB  = (const char*)(ST + ((size_t)batch * 128) * 1024);

    // DMA source bases for this thread's two slots per tile (o = i*256 + t):
    const char* sA[2];
    const char* sB[2];
#pragma unroll
    for (int i = 0; i < 2; ++i) {
        int o = i * 256 + t;
        sA[i] = adjB + (size_t)(o & 63) * 4096 + (o >> 6) * 16;   // + kb*128
        sB[i] = stB + (size_t)(o & 127) * 2048 + (o >> 7) * 16;   // + kb*64
    }

    float bv[4];
#pragma unroll
    for (int j = 0; j < 4; ++j) bv[j] = bias[wave_n + j * 16 + l16];

    f32x4 acc[2][4];
#pragma unroll
    for (int i = 0; i < 2; ++i)
#pragma unroll
        for (int j = 0; j < 4; ++j) acc[i][j] = 0.f;

    auto STAGE = [&](int kb) {          // 4 DMAs/thread, uniform count
        int buf = kb & 3;
        char* dA = &As[buf][t * 16];
        char* dB = &Bs[buf][t * 16];
#pragma unroll
        for (int i = 0; i < 2; ++i) GLD16(sA[i] + kb * 128, dA + i * 4096);
#pragma unroll
        for (int i = 0; i < 2; ++i) GLD16(sB[i] + kb * 64, dB + i * 4096);
    };

    auto COMPUTE = [&](int kb) {
        int buf = kb & 3;
        const char* A = As[buf];
        const char* B = Bs[buf];
        bf16x8 afr[2], bfr[4];
#pragma unroll
        for (int im = 0; im < 2; ++im) {
            int row = wave_m + im * 16 + l16;
            f32x4 lo = *(const f32x4*)(A + ((2 * quad) * 64 + row) * 16);
            f32x4 hi = *(const f32x4*)(A + ((2 * quad + 1) * 64 + row) * 16);
            afr[im] = cvt8(lo, hi);
        }
#pragma unroll
        for (int j = 0; j < 4; ++j)
            bfr[j] = *(const bf16x8*)(B + (quad * 128 + wave_n + j * 16 + l16) * 16);
#pragma unroll
        for (int im = 0; im < 2; ++im)
#pragma unroll
            for (int j = 0; j < 4; ++j)
                acc[im][j] = __builtin_amdgcn_mfma_f32_16x16x32_bf16(
                    afr[im], bfr[j], acc[im][j], 0, 0, 0);
    };

    // prologue: 3 tiles in flight (12 DMAs/thread)
    STAGE(0);
    STAGE(1);
    STAGE(2);
    for (int kb = 0; kb < 30; ++kb) {
        // tile kb landed when <=8 (= tiles kb+1,kb+2) remain outstanding.
        asm volatile("s_waitcnt vmcnt(8)");
        __builtin_amdgcn_s_barrier();          // all waves' tile-kb DMAs done
        __builtin_amdgcn_sched_barrier(0);     // keep ds_reads below the wait
        COMPUTE(kb);
        if (kb < 29) STAGE(kb + 3);            // refill: back to 12 in flight
        __builtin_amdgcn_sched_barrier(0);     // keep DMA issue above next wait
    }
    asm volatile("s_waitcnt vmcnt(4)");        // tile 30 landed
    __builtin_amdgcn_s_barrier();
    __builtin_amdgcn_sched_barrier(0);
    COMPUTE(30);
    asm volatile("s_waitcnt vmcnt(0)");        // tile 31 landed
    __builtin_amdgcn_s_barrier();
    __builtin_amdgcn_sched_barrier(0);
    COMPUTE(31);

    float* outb = out + ((size_t)batch * 1024 + mbase) * 128;
#pragma unroll
    for (int i = 0; i < 2; ++i)
#pragma unroll
        for (int j = 0; j < 4; ++j) {
            int n = wave_n + j * 16 + l16;
#pragma unroll
            for (int r = 0; r < 4; ++r) {
                int m = wave_m + i * 16 + quad * 4 + r;
                float v = acc[i][j][r] + bv[j];
                outb[(size_t)m * 128 + n] = fmaxf(v, 0.f);
            }
        }
}

extern "C" void kernel_launch(void* const* d_in, const int* in_sizes, int n_in,
                              void* d_out, int out_size, void* d_ws, size_t ws_size,
                              hipStream_t stream) {
    const float* x = (const float*)d_in[0];
    const float* adj = (const float*)d_in[1];
    const float* W = (const float*)d_in[2];
    const float* b = (const float*)d_in[3];
    float* out = (float*)d_out;

    // ws layout: ST bf16 [32][128][1024] = 8 MiB, then WT bf16 [128][128] = 32 KiB
    unsigned short* ST = (unsigned short*)d_ws;
    unsigned short* WT = (unsigned short*)d_ws + (size_t)32 * 128 * 1024;

    k0_wt<<<64, 256, 0, stream>>>(W, WT);
    k1_support<<<512, 256, 0, stream>>>(x, WT, ST);
    k2_gcn<<<512, 256, 0, stream>>>(adj, ST, b, out);
}